// Round 11
// baseline (667.430 us; speedup 1.0000x reference)
//
#include <hip/hip_runtime.h>
#include <cstdint>

#define GRAPHS 128

__device__ __forceinline__ int lane_bcast_i(int v, int l) {
  return __builtin_amdgcn_readlane(v, l);
}
__device__ __forceinline__ float lane_bcast_f(float v, int l) {
  return __int_as_float(__builtin_amdgcn_readlane(__float_as_int(v), l));
}
// async global->LDS DMA, 4B/lane; result consumes NO VGPRs -> compiler can't serialize
__device__ __forceinline__ void load_lds4(const float* g, float* l) {
  __builtin_amdgcn_global_load_lds(
      (const __attribute__((address_space(1))) void*)g,
      (__attribute__((address_space(3))) void*)l, 4, 0, 0);
}

// ---------------- edge prep: degree -> scan -> scatter (CSR by dst) ----------------

__global__ __launch_bounds__(256) void k_deg(const int* __restrict__ ei, int E, int ET,
                                             int* __restrict__ deg) {
  int e = blockIdx.x * 256 + threadIdx.x;
  if (e >= ET) return;
  int d = (e < E) ? ei[E + e] : (e - E);
  atomicAdd(&deg[d], 1);
}

__global__ __launch_bounds__(256) void k_s1(const int* __restrict__ deg, int N,
                                            int* __restrict__ bsum) {
  int b = blockIdx.x, tid = threadIdx.x;
  int i0 = b * 1024 + tid * 4;
  int s = 0;
#pragma unroll
  for (int e = 0; e < 4; ++e) { int i = i0 + e; if (i < N) s += deg[i]; }
#pragma unroll
  for (int o = 32; o; o >>= 1) s += __shfl_xor(s, o);
  __shared__ int wt[4];
  int lane = tid & 63, wid = tid >> 6;
  if (lane == 0) wt[wid] = s;
  __syncthreads();
  if (tid == 0) bsum[b] = wt[0] + wt[1] + wt[2] + wt[3];
}

__global__ void k_s2(int* bsum, int nb) {
  if (threadIdx.x == 0) {
    int run = 0;
    for (int i = 0; i < nb; ++i) { int t = bsum[i]; bsum[i] = run; run += t; }
  }
}

__global__ __launch_bounds__(256) void k_s3(int* __restrict__ deg_cursor,
                                            const int* __restrict__ bsum,
                                            int* __restrict__ rowptr, int N) {
  int b = blockIdx.x, tid = threadIdx.x;
  int lane = tid & 63, wid = tid >> 6;
  int i0 = b * 1024 + tid * 4;
  int d[4];
#pragma unroll
  for (int e = 0; e < 4; ++e) { int i = i0 + e; d[e] = (i < N) ? deg_cursor[i] : 0; }
  int p0 = d[0], p1 = p0 + d[1], p2 = p1 + d[2], p3 = p2 + d[3];
  int incl = p3;
#pragma unroll
  for (int o = 1; o < 64; o <<= 1) { int u = __shfl_up(incl, o); if (lane >= o) incl += u; }
  __shared__ int wt[4];
  if (lane == 63) wt[wid] = incl;
  __syncthreads();
  int woff = 0;
  for (int w = 0; w < wid; ++w) woff += wt[w];
  int ex = bsum[b] + woff + incl - p3;
  int pre[4] = {0, p0, p1, p2};
#pragma unroll
  for (int e = 0; e < 4; ++e) {
    int i = i0 + e;
    if (i < N) { int st = ex + pre[e]; deg_cursor[i] = st; rowptr[i + 1] = st + d[e]; }
  }
  if (b == 0 && tid == 0) rowptr[0] = 0;
}

__global__ __launch_bounds__(256) void k_scatter(const int* __restrict__ ei, int E, int ET,
                                                 int* __restrict__ cursor,
                                                 int* __restrict__ csrs) {
  int e = blockIdx.x * 256 + threadIdx.x;
  if (e >= ET) return;
  int s, d;
  if (e < E) { s = ei[e]; d = ei[E + e]; } else { s = d = e - E; }
  int pos = atomicAdd(&cursor[d], 1);
  csrs[pos] = s;
}

// ---------------- GEMM (64x64 tile, 4x4/thread) with fused attention dots ----------------

__global__ __launch_bounds__(256) void k_gemm_att(
    const float* __restrict__ A, const float* __restrict__ B, float* __restrict__ C,
    const float* __restrict__ attS, const float* __restrict__ attD,
    float* __restrict__ aS, float* __restrict__ aD, int M, int K, int NC, int astr) {
  __shared__ float As[64][68];
  __shared__ float Bs[64][64];
  int tid = threadIdx.x;
  int tx = tid & 15, ty = tid >> 4;
  int m0 = blockIdx.x * 64, n0 = blockIdx.y * 64;
  float acc[4][4] = {};
  for (int kc = 0; kc < K; kc += 64) {
    int r = tid >> 4;
    int f4 = tid & 15;
#pragma unroll
    for (int p = 0; p < 4; ++p) {
      int row = r + p * 16;
      int gm = m0 + row;
      float4 v = make_float4(0.f, 0.f, 0.f, 0.f);
      if (gm < M) v = *(const float4*)&A[(size_t)gm * K + kc + f4 * 4];
      As[f4 * 4 + 0][row] = v.x; As[f4 * 4 + 1][row] = v.y;
      As[f4 * 4 + 2][row] = v.z; As[f4 * 4 + 3][row] = v.w;
      float4 w = *(const float4*)&B[(size_t)(kc + row) * NC + n0 + f4 * 4];
      *(float4*)&Bs[row][f4 * 4] = w;
    }
    __syncthreads();
#pragma unroll 4
    for (int k = 0; k < 64; ++k) {
      float4 a4 = *(const float4*)&As[k][ty * 4];
      float4 b4 = *(const float4*)&Bs[k][tx * 4];
      acc[0][0] += a4.x * b4.x; acc[0][1] += a4.x * b4.y; acc[0][2] += a4.x * b4.z; acc[0][3] += a4.x * b4.w;
      acc[1][0] += a4.y * b4.x; acc[1][1] += a4.y * b4.y; acc[1][2] += a4.y * b4.z; acc[1][3] += a4.y * b4.w;
      acc[2][0] += a4.z * b4.x; acc[2][1] += a4.z * b4.y; acc[2][2] += a4.z * b4.z; acc[2][3] += a4.z * b4.w;
      acc[3][0] += a4.w * b4.x; acc[3][1] += a4.w * b4.y; acc[3][2] += a4.w * b4.z; acc[3][3] += a4.w * b4.w;
    }
    __syncthreads();
  }
  int head = blockIdx.y;
  float asv[4], adv[4];
#pragma unroll
  for (int ci = 0; ci < 4; ++ci) { asv[ci] = attS[n0 + tx * 4 + ci]; adv[ci] = attD[n0 + tx * 4 + ci]; }
#pragma unroll
  for (int ri = 0; ri < 4; ++ri) {
    int gm = m0 + ty * 4 + ri;
    float4 o; o.x = acc[ri][0]; o.y = acc[ri][1]; o.z = acc[ri][2]; o.w = acc[ri][3];
    if (gm < M) *(float4*)&C[(size_t)gm * NC + n0 + tx * 4] = o;
    float s = acc[ri][0] * asv[0] + acc[ri][1] * asv[1] + acc[ri][2] * asv[2] + acc[ri][3] * asv[3];
    float d = acc[ri][0] * adv[0] + acc[ri][1] * adv[1] + acc[ri][2] * adv[2] + acc[ri][3] * adv[3];
#pragma unroll
    for (int o2 = 1; o2 < 16; o2 <<= 1) { s += __shfl_xor(s, o2); d += __shfl_xor(d, o2); }
    if (tx == 0 && gm < M) { aS[(size_t)gm * astr + head] = s; aD[(size_t)gm * astr + head] = d; }
  }
}

// ---------------- wave-per-node softmax + aggregation (LDS-staged async gather) ----------------
// BATCH edges' rows DMA'd to per-wave LDS staging via global_load_lds (no result VGPRs ->
// all BATCH*NH loads genuinely in flight), one vmcnt wait per batch, then consume from LDS.

template <int NH, bool DOELU, bool POOLOUT>
__global__ __launch_bounds__(256) void k_agg(
    const int* __restrict__ rowptr, const int* __restrict__ csrs,
    const float* __restrict__ xp, const float* __restrict__ aS, const float* __restrict__ aD,
    const float* __restrict__ bias, float* __restrict__ out,
    const int* __restrict__ batch, float* __restrict__ pooled, float* __restrict__ gcnt, int N) {
  constexpr int ASTR = (NH == 3) ? 4 : 1;
  constexpr int BATCH = (NH == 3) ? 8 : 16;
  __shared__ float stage[4][BATCH * NH * 64];
  int wv = (blockIdx.x * blockDim.x + threadIdx.x) >> 6;
  int lane = threadIdx.x & 63;
  int wid = (threadIdx.x >> 6) & 3;
  if (wv >= N) return;
  float* st = stage[wid];
  int n = wv;
  int start = rowptr[n], end = rowptr[n + 1];
  float ad[NH], m[NH], s[NH], al[NH], cf[NH], acc[NH];
#pragma unroll
  for (int h = 0; h < NH; ++h) {
    ad[h] = aD[(size_t)n * ASTR + h];
    m[h] = -1e30f; s[h] = 0.f; al[h] = 0.f; cf[h] = 0.f; acc[h] = 0.f;
  }
  // ---- softmax phase: lane-per-edge ----
  int myS = -1;
  int j = start + lane;
  if (j < end) {
    myS = csrs[j];
    float av[NH];
    if (NH == 3) {
      float4 a4 = *(const float4*)&aS[(size_t)myS * 4];
      av[0] = a4.x; av[1] = a4.y; av[2] = a4.z;
    } else {
      av[0] = aS[myS];
    }
#pragma unroll
    for (int h = 0; h < NH; ++h) {
      float v = av[h] + ad[h];
      v = v > 0.f ? v : 0.2f * v;
      al[h] = v; m[h] = v; s[h] = 1.f;
    }
  }
  for (int jj = j + 64; jj < end; jj += 64) {  // degree > 64 (rare)
    int sb = csrs[jj];
    float av[NH];
    if (NH == 3) {
      float4 a4 = *(const float4*)&aS[(size_t)sb * 4];
      av[0] = a4.x; av[1] = a4.y; av[2] = a4.z;
    } else {
      av[0] = aS[sb];
    }
#pragma unroll
    for (int h = 0; h < NH; ++h) {
      float v = av[h] + ad[h];
      v = v > 0.f ? v : 0.2f * v;
      float M = fmaxf(m[h], v);
      s[h] = s[h] * __expf(m[h] - M) + __expf(v - M);
      m[h] = M;
    }
  }
#pragma unroll
  for (int h = 0; h < NH; ++h) {
    float mm = m[h], ss = s[h];
#pragma unroll
    for (int o = 1; o < 64; o <<= 1) {
      float om = __shfl_xor(mm, o), os = __shfl_xor(ss, o);
      float M = fmaxf(mm, om);
      ss = ss * __expf(mm - M) + os * __expf(om - M);
      mm = M;
    }
    m[h] = mm;
    s[h] = 1.0f / fmaxf(ss, 1e-16f);
  }
  if (myS >= 0) {
#pragma unroll
    for (int h = 0; h < NH; ++h) cf[h] = __expf(al[h] - m[h]) * s[h];
  }
  // ---- gather phase: BATCH-edge async LDS-staged batches ----
  for (int base = start; base < end; base += 64) {
    int cnt = min(64, end - base);
    int sreg; float dd[NH];
    if (base == start) {
      sreg = myS;
#pragma unroll
      for (int h = 0; h < NH; ++h) dd[h] = cf[h];
    } else {  // degree > 64 spillover (rare)
      int jj = base + lane; sreg = 0;
#pragma unroll
      for (int h = 0; h < NH; ++h) dd[h] = 0.f;
      if (jj < end) {
        sreg = csrs[jj];
        float av[NH];
        if (NH == 3) {
          float4 a4 = *(const float4*)&aS[(size_t)sreg * 4];
          av[0] = a4.x; av[1] = a4.y; av[2] = a4.z;
        } else {
          av[0] = aS[sreg];
        }
#pragma unroll
        for (int h = 0; h < NH; ++h) {
          float v = av[h] + ad[h];
          v = v > 0.f ? v : 0.2f * v;
          dd[h] = __expf(v - m[h]) * s[h];
        }
      }
    }
    for (int e = 0; e < cnt; e += BATCH) {
      // issue ALL DMAs first (no result registers -> structurally concurrent)
#pragma unroll
      for (int u = 0; u < BATCH; ++u) {
        int ee = min(e + u, cnt - 1);          // clamp: pad slots reload last row
        int sb = lane_bcast_i(sreg, ee);
        const float* row = xp + (size_t)sb * (NH * 64) + lane;
#pragma unroll
        for (int h = 0; h < NH; ++h)
          load_lds4(row + h * 64, st + (u * NH + h) * 64);
      }
      __builtin_amdgcn_s_waitcnt(0x0F70);      // vmcnt(0): all DMAs landed in LDS
      // consume from LDS
#pragma unroll
      for (int u = 0; u < BATCH; ++u) {
#pragma unroll
        for (int h = 0; h < NH; ++h) {
          float c = (e + u < cnt) ? lane_bcast_f(dd[h], e + u) : 0.f;
          acc[h] = fmaf(c, st[(u * NH + h) * 64 + lane], acc[h]);
        }
      }
    }
  }
  // ---- epilogue ----
  if (POOLOUT) {
    float val = acc[0] + bias[lane];
    int g = batch[n];
    atomicAdd(&pooled[g * 64 + lane], val);
    if (lane == 0) atomicAdd(&gcnt[g], 1.0f);
  } else {
#pragma unroll
    for (int h = 0; h < NH; ++h) {
      float v = acc[h] + bias[h * 64 + lane];
      if (DOELU) v = v > 0.f ? v : __expf(v) - 1.0f;
      out[(size_t)n * (NH * 64) + h * 64 + lane] = v;
    }
  }
}

// ---------------- final: mean + linear ----------------

__global__ __launch_bounds__(64) void k_final(const float* __restrict__ pooled,
                                              const float* __restrict__ gcnt,
                                              const float* __restrict__ lw,
                                              const float* __restrict__ lb,
                                              float* __restrict__ out) {
  int g = blockIdx.x, c = threadIdx.x;
  float inv = 1.0f / fmaxf(gcnt[g], 1.0f);
  float pv = pooled[g * 64 + c] * inv;
#pragma unroll
  for (int k = 0; k < 10; ++k) {
    float v = pv * lw[c * 10 + k];
#pragma unroll
    for (int o = 1; o < 64; o <<= 1) v += __shfl_xor(v, o);
    if (c == 0) out[g * 10 + k] = v + lb[k];
  }
}

extern "C" void kernel_launch(void* const* d_in, const int* in_sizes, int n_in,
                              void* d_out, int out_size, void* d_ws, size_t ws_size,
                              hipStream_t stream) {
  const float* x = (const float*)d_in[0];
  const int* ei = (const int*)d_in[1];
  const int* batch = (const int*)d_in[2];
  const float* W1 = (const float*)d_in[3];
  const float* as1 = (const float*)d_in[4];
  const float* ad1 = (const float*)d_in[5];
  const float* b1 = (const float*)d_in[6];
  const float* W2 = (const float*)d_in[7];
  const float* as2 = (const float*)d_in[8];
  const float* ad2 = (const float*)d_in[9];
  const float* b2 = (const float*)d_in[10];
  const float* lw = (const float*)d_in[11];
  const float* lb = (const float*)d_in[12];
  float* out = (float*)d_out;

  const int N = in_sizes[2];        // 50000
  const int E = in_sizes[1] / 2;    // 800000
  const int ET = E + N;             // + self loops
  const int F = in_sizes[0] / N;    // 128
  const int HC = in_sizes[6];       // 192
  const int LH = in_sizes[10];      // 64

  size_t off = 0;
  auto alo = [&](size_t bytes) -> char* {
    char* p = (char*)d_ws + off;
    off += (bytes + 255) & ~(size_t)255;
    return p;
  };
  int* cursor = (int*)alo((size_t)N * 4);
  float* pooled = (float*)alo((size_t)GRAPHS * 64 * 4);
  float* gcnt = (float*)alo((size_t)GRAPHS * 4);
  size_t zbytes = off;
  int* rowptr = (int*)alo(((size_t)N + 1) * 4);
  int* csrs = (int*)alo((size_t)ET * 4);
  float* aS1 = (float*)alo((size_t)N * 4 * 4);      // stride-4 padded
  float* aD1 = (float*)alo((size_t)N * 4 * 4);
  float* aS2 = (float*)alo((size_t)N * 4);
  float* aD2 = (float*)alo((size_t)N * 4);
  int* bsum = (int*)alo(64 * 4);
  float* xp1 = (float*)alo((size_t)N * 192 * 4);
  float* h1 = (float*)alo((size_t)N * 192 * 4);
  float* xp2 = xp1;  // xp1 dead after layer-1 aggregation

  hipMemsetAsync(d_ws, 0, zbytes, stream);
  int eb = (ET + 255) / 256;
  k_deg<<<eb, 256, 0, stream>>>(ei, E, ET, cursor);
  int nb = (N + 1023) / 1024;
  k_s1<<<nb, 256, 0, stream>>>(cursor, N, bsum);
  k_s2<<<1, 64, 0, stream>>>(bsum, nb);
  k_s3<<<nb, 256, 0, stream>>>(cursor, bsum, rowptr, N);
  k_scatter<<<eb, 256, 0, stream>>>(ei, E, ET, cursor, csrs);

  dim3 g1((N + 63) / 64, HC / 64);
  k_gemm_att<<<g1, 256, 0, stream>>>(x, W1, xp1, as1, ad1, aS1, aD1, N, F, HC, 4);
  int ab = (N + 3) / 4;
  k_agg<3, true, false><<<ab, 256, 0, stream>>>(rowptr, csrs, xp1, aS1, aD1, b1, h1,
                                                nullptr, nullptr, nullptr, N);
  dim3 g2((N + 63) / 64, LH / 64);
  k_gemm_att<<<g2, 256, 0, stream>>>(h1, W2, xp2, as2, ad2, aS2, aD2, N, HC, LH, 1);
  k_agg<1, false, true><<<ab, 256, 0, stream>>>(rowptr, csrs, xp2, aS2, aD2, b2, nullptr,
                                                batch, pooled, gcnt, N);
  k_final<<<GRAPHS, 64, 0, stream>>>(pooled, gcnt, lw, lb, out);
}

// Round 12
// 602.833 us; speedup vs baseline: 1.1072x; 1.1072x over previous
//
#include <hip/hip_runtime.h>
#include <hip/hip_fp16.h>
#include <cstdint>

#define GRAPHS 128

__device__ __forceinline__ int lane_bcast_i(int v, int l) {
  return __builtin_amdgcn_readlane(v, l);
}
__device__ __forceinline__ float lane_bcast_f(float v, int l) {
  return __int_as_float(__builtin_amdgcn_readlane(__float_as_int(v), l));
}
// async global->LDS DMA, 16B/lane (dwordx4): HW places at wave-uniform base + lane*16
__device__ __forceinline__ void load_lds16(const __half* g, __half* l) {
  __builtin_amdgcn_global_load_lds(
      (const __attribute__((address_space(1))) void*)g,
      (__attribute__((address_space(3))) void*)l, 16, 0, 0);
}
#define WAIT_VM0   __builtin_amdgcn_s_waitcnt(0x0F70)  // vmcnt(0) only
#define WAIT_LGKM0 __builtin_amdgcn_s_waitcnt(0xC07F)  // lgkmcnt(0) only

// ---------------- edge prep: degree -> scan -> scatter (CSR by dst) ----------------

__global__ __launch_bounds__(256) void k_deg(const int* __restrict__ ei, int E, int ET,
                                             int* __restrict__ deg) {
  int e = blockIdx.x * 256 + threadIdx.x;
  if (e >= ET) return;
  int d = (e < E) ? ei[E + e] : (e - E);
  atomicAdd(&deg[d], 1);
}

__global__ __launch_bounds__(256) void k_s1(const int* __restrict__ deg, int N,
                                            int* __restrict__ bsum) {
  int b = blockIdx.x, tid = threadIdx.x;
  int i0 = b * 1024 + tid * 4;
  int s = 0;
#pragma unroll
  for (int e = 0; e < 4; ++e) { int i = i0 + e; if (i < N) s += deg[i]; }
#pragma unroll
  for (int o = 32; o; o >>= 1) s += __shfl_xor(s, o);
  __shared__ int wt[4];
  int lane = tid & 63, wid = tid >> 6;
  if (lane == 0) wt[wid] = s;
  __syncthreads();
  if (tid == 0) bsum[b] = wt[0] + wt[1] + wt[2] + wt[3];
}

__global__ void k_s2(int* bsum, int nb) {
  if (threadIdx.x == 0) {
    int run = 0;
    for (int i = 0; i < nb; ++i) { int t = bsum[i]; bsum[i] = run; run += t; }
  }
}

__global__ __launch_bounds__(256) void k_s3(int* __restrict__ deg_cursor,
                                            const int* __restrict__ bsum,
                                            int* __restrict__ rowptr, int N) {
  int b = blockIdx.x, tid = threadIdx.x;
  int lane = tid & 63, wid = tid >> 6;
  int i0 = b * 1024 + tid * 4;
  int d[4];
#pragma unroll
  for (int e = 0; e < 4; ++e) { int i = i0 + e; d[e] = (i < N) ? deg_cursor[i] : 0; }
  int p0 = d[0], p1 = p0 + d[1], p2 = p1 + d[2], p3 = p2 + d[3];
  int incl = p3;
#pragma unroll
  for (int o = 1; o < 64; o <<= 1) { int u = __shfl_up(incl, o); if (lane >= o) incl += u; }
  __shared__ int wt[4];
  if (lane == 63) wt[wid] = incl;
  __syncthreads();
  int woff = 0;
  for (int w = 0; w < wid; ++w) woff += wt[w];
  int ex = bsum[b] + woff + incl - p3;
  int pre[4] = {0, p0, p1, p2};
#pragma unroll
  for (int e = 0; e < 4; ++e) {
    int i = i0 + e;
    if (i < N) { int st = ex + pre[e]; deg_cursor[i] = st; rowptr[i + 1] = st + d[e]; }
  }
  if (b == 0 && tid == 0) rowptr[0] = 0;
}

__global__ __launch_bounds__(256) void k_scatter(const int* __restrict__ ei, int E, int ET,
                                                 int* __restrict__ cursor,
                                                 int* __restrict__ csrs) {
  int e = blockIdx.x * 256 + threadIdx.x;
  if (e >= ET) return;
  int s, d;
  if (e < E) { s = ei[e]; d = ei[E + e]; } else { s = d = e - E; }
  int pos = atomicAdd(&cursor[d], 1);
  csrs[pos] = s;
}

// ---------------- GEMM (64x64 tile, 4x4/thread), fp16 C, fused attention dots ----------------

__global__ __launch_bounds__(256) void k_gemm_att(
    const float* __restrict__ A, const float* __restrict__ B, __half* __restrict__ C,
    const float* __restrict__ attS, const float* __restrict__ attD,
    float* __restrict__ aS, float* __restrict__ aD, int M, int K, int NC, int astr) {
  __shared__ float As[64][68];
  __shared__ float Bs[64][64];
  int tid = threadIdx.x;
  int tx = tid & 15, ty = tid >> 4;
  int m0 = blockIdx.x * 64, n0 = blockIdx.y * 64;
  float acc[4][4] = {};
  for (int kc = 0; kc < K; kc += 64) {
    int r = tid >> 4;
    int f4 = tid & 15;
#pragma unroll
    for (int p = 0; p < 4; ++p) {
      int row = r + p * 16;
      int gm = m0 + row;
      float4 v = make_float4(0.f, 0.f, 0.f, 0.f);
      if (gm < M) v = *(const float4*)&A[(size_t)gm * K + kc + f4 * 4];
      As[f4 * 4 + 0][row] = v.x; As[f4 * 4 + 1][row] = v.y;
      As[f4 * 4 + 2][row] = v.z; As[f4 * 4 + 3][row] = v.w;
      float4 w = *(const float4*)&B[(size_t)(kc + row) * NC + n0 + f4 * 4];
      *(float4*)&Bs[row][f4 * 4] = w;
    }
    __syncthreads();
#pragma unroll 4
    for (int k = 0; k < 64; ++k) {
      float4 a4 = *(const float4*)&As[k][ty * 4];
      float4 b4 = *(const float4*)&Bs[k][tx * 4];
      acc[0][0] += a4.x * b4.x; acc[0][1] += a4.x * b4.y; acc[0][2] += a4.x * b4.z; acc[0][3] += a4.x * b4.w;
      acc[1][0] += a4.y * b4.x; acc[1][1] += a4.y * b4.y; acc[1][2] += a4.y * b4.z; acc[1][3] += a4.y * b4.w;
      acc[2][0] += a4.z * b4.x; acc[2][1] += a4.z * b4.y; acc[2][2] += a4.z * b4.z; acc[2][3] += a4.z * b4.w;
      acc[3][0] += a4.w * b4.x; acc[3][1] += a4.w * b4.y; acc[3][2] += a4.w * b4.z; acc[3][3] += a4.w * b4.w;
    }
    __syncthreads();
  }
  int head = blockIdx.y;
  float asv[4], adv[4];
#pragma unroll
  for (int ci = 0; ci < 4; ++ci) { asv[ci] = attS[n0 + tx * 4 + ci]; adv[ci] = attD[n0 + tx * 4 + ci]; }
#pragma unroll
  for (int ri = 0; ri < 4; ++ri) {
    int gm = m0 + ty * 4 + ri;
    if (gm < M) {
      __half2 p01 = __halves2half2(__float2half(acc[ri][0]), __float2half(acc[ri][1]));
      __half2 p23 = __halves2half2(__float2half(acc[ri][2]), __float2half(acc[ri][3]));
      size_t cidx = (size_t)gm * NC + n0 + tx * 4;
      *(__half2*)&C[cidx] = p01;
      *(__half2*)&C[cidx + 2] = p23;
    }
    float s = acc[ri][0] * asv[0] + acc[ri][1] * asv[1] + acc[ri][2] * asv[2] + acc[ri][3] * asv[3];
    float d = acc[ri][0] * adv[0] + acc[ri][1] * adv[1] + acc[ri][2] * adv[2] + acc[ri][3] * adv[3];
#pragma unroll
    for (int o2 = 1; o2 < 16; o2 <<= 1) { s += __shfl_xor(s, o2); d += __shfl_xor(d, o2); }
    if (tx == 0 && gm < M) { aS[(size_t)gm * astr + head] = s; aD[(size_t)gm * astr + head] = d; }
  }
}

// ---------------- wave-per-node softmax + wide-DMA fp16 LDS-staged aggregation ----------------
// NH==3: fp16 row = 384B; 1 width-16 DMA covers 2 rows (lanes 0-23 edge A, 24-47 edge B,
//        48-63 clamped) -> 4 DMA instrs per 8-edge batch, 6 cache lines/edge (vs 12 fp32).
// NH==1: fp16 row = 128B; 1 DMA covers 8 rows -> 2 instrs per 16-edge batch, 2 lines/edge.

template <int NH, bool DOELU, bool POOLOUT>
__global__ __launch_bounds__(256) void k_agg(
    const int* __restrict__ rowptr, const int* __restrict__ csrs,
    const __half* __restrict__ xp, const float* __restrict__ aS, const float* __restrict__ aD,
    const float* __restrict__ bias, float* __restrict__ out,
    const int* __restrict__ batch, float* __restrict__ pooled, float* __restrict__ gcnt, int N) {
  constexpr int ASTR = (NH == 3) ? 4 : 1;
  constexpr int BATCH = (NH == 3) ? 8 : 16;
  constexpr int STH = (NH == 3) ? 2048 : 1024;   // halves per wave slot
  __shared__ __half stage[4][STH];
  int wv = (blockIdx.x * blockDim.x + threadIdx.x) >> 6;
  int lane = threadIdx.x & 63;
  int wid = (threadIdx.x >> 6) & 3;
  if (wv >= N) return;
  __half* st = stage[wid];
  int n = wv;
  int start = rowptr[n], end = rowptr[n + 1];
  float ad[NH], m[NH], s[NH], al[NH], cf[NH], acc[NH];
#pragma unroll
  for (int h = 0; h < NH; ++h) {
    ad[h] = aD[(size_t)n * ASTR + h];
    m[h] = -1e30f; s[h] = 0.f; al[h] = 0.f; cf[h] = 0.f; acc[h] = 0.f;
  }
  // ---- softmax phase: lane-per-edge ----
  int myS = -1;
  int j = start + lane;
  if (j < end) {
    myS = csrs[j];
    float av[NH];
    if (NH == 3) {
      float4 a4 = *(const float4*)&aS[(size_t)myS * 4];
      av[0] = a4.x; av[1] = a4.y; av[2] = a4.z;
    } else {
      av[0] = aS[myS];
    }
#pragma unroll
    for (int h = 0; h < NH; ++h) {
      float v = av[h] + ad[h];
      v = v > 0.f ? v : 0.2f * v;
      al[h] = v; m[h] = v; s[h] = 1.f;
    }
  }
  for (int jj = j + 64; jj < end; jj += 64) {  // degree > 64 (rare)
    int sb = csrs[jj];
    float av[NH];
    if (NH == 3) {
      float4 a4 = *(const float4*)&aS[(size_t)sb * 4];
      av[0] = a4.x; av[1] = a4.y; av[2] = a4.z;
    } else {
      av[0] = aS[sb];
    }
#pragma unroll
    for (int h = 0; h < NH; ++h) {
      float v = av[h] + ad[h];
      v = v > 0.f ? v : 0.2f * v;
      float M = fmaxf(m[h], v);
      s[h] = s[h] * __expf(m[h] - M) + __expf(v - M);
      m[h] = M;
    }
  }
#pragma unroll
  for (int h = 0; h < NH; ++h) {
    float mm = m[h], ss = s[h];
#pragma unroll
    for (int o = 1; o < 64; o <<= 1) {
      float om = __shfl_xor(mm, o), os = __shfl_xor(ss, o);
      float M = fmaxf(mm, om);
      ss = ss * __expf(mm - M) + os * __expf(om - M);
      mm = M;
    }
    m[h] = mm;
    s[h] = 1.0f / fmaxf(ss, 1e-16f);
  }
  if (myS >= 0) {
#pragma unroll
    for (int h = 0; h < NH; ++h) cf[h] = __expf(al[h] - m[h]) * s[h];
  }
  // ---- gather phase ----
  for (int base = start; base < end; base += 64) {
    int cnt = min(64, end - base);
    int sreg; float dd[NH];
    if (base == start) {
      sreg = myS;
#pragma unroll
      for (int h = 0; h < NH; ++h) dd[h] = cf[h];
    } else {  // degree > 64 spillover (rare)
      int jj = base + lane; sreg = 0;
#pragma unroll
      for (int h = 0; h < NH; ++h) dd[h] = 0.f;
      if (jj < end) {
        sreg = csrs[jj];
        float av[NH];
        if (NH == 3) {
          float4 a4 = *(const float4*)&aS[(size_t)sreg * 4];
          av[0] = a4.x; av[1] = a4.y; av[2] = a4.z;
        } else {
          av[0] = aS[sreg];
        }
#pragma unroll
        for (int h = 0; h < NH; ++h) {
          float v = av[h] + ad[h];
          v = v > 0.f ? v : 0.2f * v;
          dd[h] = __expf(v - m[h]) * s[h];
        }
      }
    }
    for (int e = 0; e < cnt; e += BATCH) {
      WAIT_LGKM0;  // prior batch's LDS reads drained before DMA overwrites slot
      if (NH == 3) {
#pragma unroll
        for (int k = 0; k < 4; ++k) {
          int eA = min(e + 2 * k, cnt - 1), eB = min(e + 2 * k + 1, cnt - 1);
          int sA = lane_bcast_i(sreg, eA), sB = lane_bcast_i(sreg, eB);
          int piece = (lane < 24) ? lane : ((lane < 48) ? lane - 24 : 23);
          int sb = (lane < 24) ? sA : sB;
          const __half* g = xp + (size_t)sb * 192 + piece * 8;
          load_lds16(g, st + k * 512);   // 512 halves = 1024B slot (2 rows + scratch)
        }
      } else {
#pragma unroll
        for (int k = 0; k < 2; ++k) {
          int ee = min(e + 8 * k + (lane >> 3), cnt - 1);
          int sb = __shfl(sreg, ee);
          const __half* g = xp + (size_t)sb * 64 + (lane & 7) * 8;
          load_lds16(g, st + k * 512);   // 8 rows of 64 halves
        }
      }
      WAIT_VM0;  // all DMAs landed in LDS
#pragma unroll
      for (int u = 0; u < BATCH; ++u) {
        const __half* eb;
        if (NH == 3) eb = st + (u >> 1) * 512 + (u & 1) * 192;
        else eb = st + (u >> 3) * 512 + (u & 7) * 64;
#pragma unroll
        for (int h = 0; h < NH; ++h) {
          float c = (e + u < cnt) ? lane_bcast_f(dd[h], e + u) : 0.f;
          acc[h] = fmaf(c, __half2float(eb[h * 64 + lane]), acc[h]);
        }
      }
    }
  }
  // ---- epilogue ----
  if (POOLOUT) {
    float val = acc[0] + bias[lane];
    int g = batch[n];
    atomicAdd(&pooled[g * 64 + lane], val);
    if (lane == 0) atomicAdd(&gcnt[g], 1.0f);
  } else {
#pragma unroll
    for (int h = 0; h < NH; ++h) {
      float v = acc[h] + bias[h * 64 + lane];
      if (DOELU) v = v > 0.f ? v : __expf(v) - 1.0f;
      out[(size_t)n * (NH * 64) + h * 64 + lane] = v;
    }
  }
}

// ---------------- final: mean + linear ----------------

__global__ __launch_bounds__(64) void k_final(const float* __restrict__ pooled,
                                              const float* __restrict__ gcnt,
                                              const float* __restrict__ lw,
                                              const float* __restrict__ lb,
                                              float* __restrict__ out) {
  int g = blockIdx.x, c = threadIdx.x;
  float inv = 1.0f / fmaxf(gcnt[g], 1.0f);
  float pv = pooled[g * 64 + c] * inv;
#pragma unroll
  for (int k = 0; k < 10; ++k) {
    float v = pv * lw[c * 10 + k];
#pragma unroll
    for (int o = 1; o < 64; o <<= 1) v += __shfl_xor(v, o);
    if (c == 0) out[g * 10 + k] = v + lb[k];
  }
}

extern "C" void kernel_launch(void* const* d_in, const int* in_sizes, int n_in,
                              void* d_out, int out_size, void* d_ws, size_t ws_size,
                              hipStream_t stream) {
  const float* x = (const float*)d_in[0];
  const int* ei = (const int*)d_in[1];
  const int* batch = (const int*)d_in[2];
  const float* W1 = (const float*)d_in[3];
  const float* as1 = (const float*)d_in[4];
  const float* ad1 = (const float*)d_in[5];
  const float* b1 = (const float*)d_in[6];
  const float* W2 = (const float*)d_in[7];
  const float* as2 = (const float*)d_in[8];
  const float* ad2 = (const float*)d_in[9];
  const float* b2 = (const float*)d_in[10];
  const float* lw = (const float*)d_in[11];
  const float* lb = (const float*)d_in[12];
  float* out = (float*)d_out;

  const int N = in_sizes[2];        // 50000
  const int E = in_sizes[1] / 2;    // 800000
  const int ET = E + N;             // + self loops
  const int F = in_sizes[0] / N;    // 128
  const int HC = in_sizes[6];       // 192
  const int LH = in_sizes[10];      // 64

  size_t off = 0;
  auto alo = [&](size_t bytes) -> char* {
    char* p = (char*)d_ws + off;
    off += (bytes + 255) & ~(size_t)255;
    return p;
  };
  int* cursor = (int*)alo((size_t)N * 4);
  float* pooled = (float*)alo((size_t)GRAPHS * 64 * 4);
  float* gcnt = (float*)alo((size_t)GRAPHS * 4);
  size_t zbytes = off;
  int* rowptr = (int*)alo(((size_t)N + 1) * 4);
  int* csrs = (int*)alo((size_t)ET * 4);
  float* aS1 = (float*)alo((size_t)N * 4 * 4);      // stride-4 padded
  float* aD1 = (float*)alo((size_t)N * 4 * 4);
  float* aS2 = (float*)alo((size_t)N * 4);
  float* aD2 = (float*)alo((size_t)N * 4);
  int* bsum = (int*)alo(64 * 4);
  __half* xp1 = (__half*)alo((size_t)N * 192 * 2 + 512);
  float* h1 = (float*)alo((size_t)N * 192 * 4);
  __half* xp2 = (__half*)alo((size_t)N * 64 * 2 + 512);

  hipMemsetAsync(d_ws, 0, zbytes, stream);
  int eb = (ET + 255) / 256;
  k_deg<<<eb, 256, 0, stream>>>(ei, E, ET, cursor);
  int nb = (N + 1023) / 1024;
  k_s1<<<nb, 256, 0, stream>>>(cursor, N, bsum);
  k_s2<<<1, 64, 0, stream>>>(bsum, nb);
  k_s3<<<nb, 256, 0, stream>>>(cursor, bsum, rowptr, N);
  k_scatter<<<eb, 256, 0, stream>>>(ei, E, ET, cursor, csrs);

  dim3 g1((N + 63) / 64, HC / 64);
  k_gemm_att<<<g1, 256, 0, stream>>>(x, W1, xp1, as1, ad1, aS1, aD1, N, F, HC, 4);
  int ab = (N + 3) / 4;
  k_agg<3, true, false><<<ab, 256, 0, stream>>>(rowptr, csrs, xp1, aS1, aD1, b1, h1,
                                                nullptr, nullptr, nullptr, N);
  dim3 g2((N + 63) / 64, LH / 64);
  k_gemm_att<<<g2, 256, 0, stream>>>(h1, W2, xp2, as2, ad2, aS2, aD2, N, HC, LH, 1);
  k_agg<1, false, true><<<ab, 256, 0, stream>>>(rowptr, csrs, xp2, aS2, aD2, b2, nullptr,
                                                batch, pooled, gcnt, N);
  k_final<<<GRAPHS, 64, 0, stream>>>(pooled, gcnt, lw, lb, out);
}